// Round 8
// baseline (294.395 us; speedup 1.0000x reference)
//
#include <hip/hip_runtime.h>
#include <math.h>

// Problem constants
#define B_    128
#define T_    2048
#define DIN   128
#define HID_  132
#define DOUT  64

// Tiling
#define TC    128            // time-steps per fused block
#define NCC   (T_ / TC)      // 16 chunks
#define AS    168            // act row stride (f16): 336B, 16B-aligned

typedef _Float16 half8   __attribute__((ext_vector_type(8)));
typedef _Float16 half4v  __attribute__((ext_vector_type(4)));
typedef float    float4v __attribute__((ext_vector_type(4)));

// lgkm-only barrier: drains LDS ops and syncs the block WITHOUT waiting on
// in-flight global (vmcnt) loads -- weight prefetches survive the barrier.
// sched_barrier(0x7F) lets VALU/SALU/MFMA/VMEM cross but pins DS ops.
#define LBAR()                                                   \
    do {                                                         \
        asm volatile("s_waitcnt lgkmcnt(0)" ::: "memory");       \
        __builtin_amdgcn_s_barrier();                            \
        __builtin_amdgcn_sched_barrier(0x7F);                    \
    } while (0)

__device__ __forceinline__ float4v max4(float4v a, float4v b) {
    float4v r;
#pragma unroll
    for (int i = 0; i < 4; ++i) r[i] = fmaxf(a[i], b[i]);
    return r;
}

// elementwise f16 max (clang emits v_pk_max_f16 pairs; no NaNs in data)
__device__ __forceinline__ half8 hmax8(half8 a, half8 b) {
    half8 r;
#pragma unroll
    for (int i = 0; i < 8; ++i) r[i] = (a[i] > b[i]) ? a[i] : b[i];
    return r;
}

// ---------------------------------------------------------------------------
// Kernel 1: blocks [0,32): weight prep into fragment-ordered layout.
//           blocks [32, 32+2048): per-(b,chunk) WITHIN-CHUNK SUFFIX MAX of P,
//             written as f16 S16 (67MB, L3-hot for kernel 2), plus f16 chunk
//             max cmax16. All the suffix work rides the mandatory 134MB P
//             stream -- kernel 2 never touches f32 P again.
// Weight swizzle (per layer, rows R, padded K = KP): element (k, n) lives at
//   ci=k/64, kr=k%64, kc=min(64,KP-64ci), g=kr/8, j=kr%8, h=g/4, q=g%4
//   off = ci*R*64 + (n/16)*16*kc + h*512 + q*128 + (n%16)*8 + j
// so lane (quad,l16) of a wave reads its half8 A-fragment for (kt, nt) at
//   SW + ci*R*64 + kt2*512 + nt*16*kc + quad*128 + l16*8  (contiguous 1KB).
// ---------------------------------------------------------------------------
__global__ __launch_bounds__(256) void prep_kernel(
    const float* __restrict__ P,
    const float* __restrict__ W1, const float* __restrict__ b1,
    const float* __restrict__ W2, const float* __restrict__ b2,
    const float* __restrict__ W3, const float* __restrict__ b3,
    const float* __restrict__ W4, const float* __restrict__ b4,
    _Float16* __restrict__ S16, _Float16* __restrict__ cmax16,
    _Float16* __restrict__ SW1, _Float16* __restrict__ SW2,
    _Float16* __restrict__ SW3, _Float16* __restrict__ SW4,
    float* __restrict__ bpad) {
    const int bid = blockIdx.x;
    const int tid = threadIdx.x;
    if (bid >= 32) {
        // ---- suffix max: (c4 0..31 covering d) x (sg 0..7 16-row segments)
        __shared__ float4v smax1[256];
        const int cb = bid - 32;
        const int b = cb >> 4, c = cb & 15;
        const int c4 = tid & 31, sg = tid >> 5;
        const float* p = P + ((size_t)(b * T_ + c * TC + sg * 16)) * DIN + c4 * 4;
        float4v v[16];
#pragma unroll
        for (int i = 0; i < 16; ++i)        // all 16 HBM loads in flight
            v[i] = *(const float4v*)(p + (size_t)i * DIN);
        float4v run = {-INFINITY, -INFINITY, -INFINITY, -INFINITY};
#pragma unroll
        for (int i = 15; i >= 0; --i) {     // v[i] := suffix max within segment
            run = max4(run, v[i]);
            v[i] = run;
        }
        smax1[sg * 32 + c4] = run;
        __syncthreads();
        float4v tail = {-INFINITY, -INFINITY, -INFINITY, -INFINITY};
        for (int s = sg + 1; s < 8; ++s) tail = max4(tail, smax1[s * 32 + c4]);
        // S16[row] = f16(max(seg-suffix, later-segments)) -- within-chunk suffix
        _Float16* s16 = S16 + ((size_t)(b * T_ + c * TC + sg * 16)) * DIN + c4 * 4;
#pragma unroll
        for (int i = 0; i < 16; ++i) {
            float4v f = max4(v[i], tail);
            half4v h;
#pragma unroll
            for (int j = 0; j < 4; ++j) h[j] = (_Float16)f[j];
            *(half4v*)(s16 + (size_t)i * DIN) = h;
        }
        if (tid < 32) {   // chunk max (f16; rounding is monotone => exact)
            float4v r = smax1[tid];
#pragma unroll
            for (int s = 1; s < 8; ++s) r = max4(r, smax1[s * 32 + tid]);
            half4v h;
#pragma unroll
            for (int j = 0; j < 4; ++j) h[j] = (_Float16)r[j];
            *(half4v*)(cmax16 + ((size_t)b * NCC + c) * DIN + tid * 4) = h;
        }
    } else {
        // ---- weight prep: 8 slice-blocks per layer, coalesced row reads ----
        const int l = bid >> 3, slice = bid & 7;
        const float *W, *bs; _Float16* dst; int K, N, KP, R, NB;
        if (l == 0)      { W = W1; bs = b1; dst = SW1; K = 128; N = 132; KP = 128; R = 144; NB = 132; }
        else if (l == 1) { W = W2; bs = b2; dst = SW2; K = 132; N = 132; KP = 160; R = 144; NB = 132; }
        else if (l == 2) { W = W3; bs = b3; dst = SW3; K = 132; N = 132; KP = 160; R = 144; NB = 132; }
        else             { W = W4; bs = b4; dst = SW4; K = 132; N = 64;  KP = 160; R = 64;  NB = 64;  }
        for (int k = slice; k < KP; k += 8) {
            const int ci = k >> 6, kr = k & 63;
            const int kc = (KP - (ci << 6) < 64) ? 32 : 64;
            const int g = kr >> 3, j = kr & 7, h = g >> 2, q = g & 3;
            for (int n = tid; n < R; n += 256) {
                float v = (k < K && n < N) ? W[(size_t)k * N + n] : 0.f;
                size_t off = (size_t)ci * R * 64 + (size_t)(n >> 4) * 16 * kc +
                             h * 512 + q * 128 + (n & 15) * 8 + j;
                dst[off] = (_Float16)v;
            }
        }
        if (slice == 0)
            for (int i = tid; i < 144; i += 256)
                bpad[l * 144 + i] = (i < NB) ? bs[i] : 0.f;
    }
}

// ---------------------------------------------------------------------------
// K-loop of one layer for one wave (2x2 wave grid: wt splits rows, wn splits
// n-tiles). Wave (wn,wt) computes C[j][s] for n-tiles NTBASE..NTBASE+NTW-1
// and strips s=0..3 of rows [64wt, 64wt+64). Each weight fragment is read by
// EXACTLY ONE wave (146KB/block total = minimum), and feeds 4 MFMAs.
// No barriers inside; caller places lgkm-only barriers.
// ---------------------------------------------------------------------------
template <int NT, int KTOT, int NTW, int NTBASE>
__device__ __forceinline__ void kloop(const _Float16* __restrict__ Wsw,
                                      const _Float16* __restrict__ act,
                                      float4v (&C)[5][4],
                                      int wt, int quad, int l16) {
    constexpr int NKT = KTOT / 32;
    constexpr int R = NT * 16;
#pragma unroll
    for (int j = 0; j < NTW; ++j)
#pragma unroll
        for (int s = 0; s < 4; ++s) C[j][s] = (float4v)0.0f;

    const _Float16* wb = Wsw + quad * 128 + l16 * 8;
    const _Float16* ab = act + (size_t)(64 * wt + l16) * AS + quad * 8;
#pragma unroll
    for (int kt = 0; kt < NKT; ++kt) {
        const int ci = kt >> 1, kt2 = kt & 1;              // compile-time after unroll
        const int kc = (KTOT - ci * 64 < 64) ? 32 : 64;
        half8 a[4];
#pragma unroll
        for (int s = 0; s < 4; ++s)
            a[s] = *(const half8*)(ab + (size_t)(16 * s) * AS + kt * 32);
#pragma unroll
        for (int j = 0; j < NTW; ++j) {
            const int nt = NTBASE + j;
            half8 w = *(const half8*)(wb + ci * (R * 64) + kt2 * 512 + nt * 16 * kc);
#pragma unroll
            for (int s = 0; s < 4; ++s)
                C[j][s] = __builtin_amdgcn_mfma_f32_16x16x32_f16(w, a[s], C[j][s], 0, 0, 0);
        }
    }
}

// ---------------------------------------------------------------------------
// Epilogue: bias + ReLU + f16 store to act (or sigmoid + f32 store to global).
// Wave writes rows [64wt,64wt+64) x cols [NTBASE*16, (NTBASE+NTW)*16) --
// disjoint across waves; caller barriers order it vs. reads.
// ---------------------------------------------------------------------------
template <int NTW, int NTBASE, bool LAST>
__device__ __forceinline__ void epi(float4v (&C)[5][4],
                                    const float* __restrict__ bp,
                                    _Float16* act, float* __restrict__ outg,
                                    int wt, int quad, int l16) {
#pragma unroll
    for (int j = 0; j < NTW; ++j) {
        const int n0 = (NTBASE + j) * 16 + quad * 4;
        float4v bv = *(const float4v*)(bp + n0);
#pragma unroll
        for (int s = 0; s < 4; ++s) {
            const int m = 64 * wt + 16 * s + l16;
            float4v c = C[j][s];
            if (LAST) {
                float4v o;
#pragma unroll
                for (int r = 0; r < 4; ++r)
                    o[r] = 1.f / (1.f + __expf(-5.f * (c[r] + bv[r])));
                *(float4v*)(outg + (size_t)m * DOUT + n0) = o;
            } else {
                half4v hv;
#pragma unroll
                for (int r = 0; r < 4; ++r)
                    hv[r] = (_Float16)fmaxf(c[r] + bv[r], 0.f);
                *(half4v*)(act + (size_t)m * AS + n0) = hv;
            }
        }
    }
}

// ---------------------------------------------------------------------------
// Fused kernel: phase-1 is now a thin f16 gather: load within-chunk suffix
// S16 (L3-hot), fold the later-chunk tail from cmax16, store to act. Then
// 4 MFMA layers on a 2x2 wave grid (wt = row half, wn = n-tile half; weight
// traffic = 146KB/block minimum). All barriers lgkm-only (no vmcnt drain).
// LDS = act 43008B -> 3 blocks/CU (12 waves/CU).
// ---------------------------------------------------------------------------
__global__ __launch_bounds__(256, 3) void fused_kernel(
    const _Float16* __restrict__ S16, const _Float16* __restrict__ cmax16,
    const _Float16* __restrict__ SW1, const _Float16* __restrict__ SW2,
    const _Float16* __restrict__ SW3, const _Float16* __restrict__ SW4,
    const float* __restrict__ bpad, float* __restrict__ Out) {
    __shared__ __align__(16) _Float16 act[TC * AS];      // 43008 B

    const int bid = blockIdx.x;
    const int b = bid / NCC, c = bid % NCC;
    const int tid = threadIdx.x;
    const int wave = tid >> 6, lane = tid & 63;
    const int quad = lane >> 4, l16 = lane & 15;
    const int wt = wave & 1, wn = wave >> 1;

    float4v C[5][4];   // accumulators: up to 5 n-tiles x 4 strips

    {   // zero K-pad cols [144,160) (read as A-operand by layers 2-4)
        const int m = tid >> 1, s2 = tid & 1;
        uint4 z{0, 0, 0, 0};
        *(uint4*)(act + (size_t)m * AS + 144 + s2 * 8) = z;
    }
    {   // phase-1: act[row] = max(S16[row], tail(cmax16 of later chunks))
        // (c8 0..15 covering 8 cols each) x (sg 0..15 covering 8 rows each);
        // wave w touches rows [32w,32w+32) -- wave-private, no barrier needed
        const int c8 = tid & 15, sg = tid >> 4;
        const _Float16* sp = S16 + ((size_t)(b * T_ + c * TC + sg * 8)) * DIN + c8 * 8;
        half8 v[8];
#pragma unroll
        for (int i = 0; i < 8; ++i)          // 8 L3-hot loads in flight
            v[i] = *(const half8*)(sp + (size_t)i * DIN);
        half8 tl;
#pragma unroll
        for (int j = 0; j < 8; ++j) tl[j] = (_Float16)(-INFINITY);
#pragma unroll
        for (int j = 1; j < NCC; ++j) {      // later-chunk tail, clamped+predicated
            const int jj = c + j;
            const int jc = (jj < NCC - 1) ? jj : NCC - 1;
            half8 t = *(const half8*)(cmax16 + ((size_t)b * NCC + jc) * DIN + c8 * 8);
            if (jj < NCC) tl = hmax8(tl, t); // block-uniform predicate
        }
#pragma unroll
        for (int i = 0; i < 8; ++i)
            *(half8*)(act + (size_t)(sg * 8 + i) * AS + c8 * 8) = hmax8(v[i], tl);
    }
    LBAR();   // phase-1 act writes visible to all waves

    float* outg = Out + (size_t)(b * T_ + c * TC) * DOUT;

    // ---- layer 1 (K=128, NT=9: wn0 tiles 0-4, wn1 tiles 5-8) ----
    if (wn == 0) kloop<9, 128, 5, 0>(SW1, act, C, wt, quad, l16);
    else         kloop<9, 128, 4, 5>(SW1, act, C, wt, quad, l16);
    LBAR();   // all act reads done before in-place overwrite
    if (wn == 0) epi<5, 0, false>(C, bpad, act, nullptr, wt, quad, l16);
    else         epi<4, 5, false>(C, bpad, act, nullptr, wt, quad, l16);
    LBAR();   // layer-1 writes visible

    // ---- layer 2 (K=160) ----
    if (wn == 0) kloop<9, 160, 5, 0>(SW2, act, C, wt, quad, l16);
    else         kloop<9, 160, 4, 5>(SW2, act, C, wt, quad, l16);
    LBAR();
    if (wn == 0) epi<5, 0, false>(C, bpad + 144, act, nullptr, wt, quad, l16);
    else         epi<4, 5, false>(C, bpad + 144, act, nullptr, wt, quad, l16);
    LBAR();

    // ---- layer 3 (K=160) ----
    if (wn == 0) kloop<9, 160, 5, 0>(SW3, act, C, wt, quad, l16);
    else         kloop<9, 160, 4, 5>(SW3, act, C, wt, quad, l16);
    LBAR();
    if (wn == 0) epi<5, 0, false>(C, bpad + 288, act, nullptr, wt, quad, l16);
    else         epi<4, 5, false>(C, bpad + 288, act, nullptr, wt, quad, l16);
    LBAR();

    // ---- layer 4 (K=160, NT=4: 2 tiles each; writes global, no barrier) ----
    if (wn == 0) kloop<4, 160, 2, 0>(SW4, act, C, wt, quad, l16);
    else         kloop<4, 160, 2, 2>(SW4, act, C, wt, quad, l16);
    if (wn == 0) epi<2, 0, true>(C, bpad + 432, act, outg, wt, quad, l16);
    else         epi<2, 2, true>(C, bpad + 432, act, outg, wt, quad, l16);
}

// ---------------------------------------------------------------------------
extern "C" void kernel_launch(void* const* d_in, const int* in_sizes, int n_in,
                              void* d_out, int out_size, void* d_ws, size_t ws_size,
                              hipStream_t stream) {
    const float* P  = (const float*)d_in[0];
    const float* W1 = (const float*)d_in[1];
    const float* b1 = (const float*)d_in[2];
    const float* W2 = (const float*)d_in[3];
    const float* b2 = (const float*)d_in[4];
    const float* W3 = (const float*)d_in[5];
    const float* b3 = (const float*)d_in[6];
    const float* W4 = (const float*)d_in[7];
    const float* b4 = (const float*)d_in[8];
    float* out = (float*)d_out;

    // ws layout (d_ws is 512MiB per the harness fill; we use ~66MiB)
    char* ws = (char*)d_ws;
    _Float16* cmax16 = (_Float16*)ws;                     // 128*16*128 f16 = 512KB
    _Float16* SW1  = (_Float16*)(ws + (1 << 20));         // 144*128 f16 (frag-ordered)
    _Float16* SW2  = SW1 + 144 * 128;                     // 144*160
    _Float16* SW3  = SW2 + 144 * 160;                     // 144*160
    _Float16* SW4  = SW3 + 144 * 160;                     // 64*160
    float*    bpad = (float*)(SW4 + 64 * 160);            // 4*144 f32
    _Float16* S16  = (_Float16*)(ws + (2 << 20));         // 128*2048*128 f16 = 64MiB

    prep_kernel<<<B_ * NCC + 32, 256, 0, stream>>>(
        P, W1, b1, W2, b2, W3, b3, W4, b4, S16, cmax16, SW1, SW2, SW3, SW4, bpad);
    fused_kernel<<<B_ * NCC, 256, 0, stream>>>(S16, cmax16, SW1, SW2, SW3, SW4,
                                               bpad, out);
}